// Round 14
// baseline (316.441 us; speedup 1.0000x reference)
//
#include <hip/hip_runtime.h>
#include <hip/hip_bf16.h>

// NoisyActLin: y = fakequant(x) @ fakequant(W).T + bias
// x: [4,2048,2048] f32 -> M=8192, K=2048 ; W: [8192,2048] f32 -> N=8192
// out: [8192, 8192] f32
//
// R14: cross-block overlap (m114). R13 closed the model: LDS port (2304cyc)
// and MFMA (2483cyc) are 100% serialized inside one barrier-locked block.
// Fix: 256-thread blocks (4 waves, 2Mx2N, 128x64/wave), 48KB LDS, BK=32,
// launch_bounds(256,2) -> ~200 regs, no spill (R9's mechanism, minus R9's
// reg-cap mistake) -> 2-3 co-resident blocks/CU interleave port and MFMA.
// Wait discipline (R6/R8): lands-guarantee = own-wave vmcnt(0) BEFORE BAR.
// Swizzle: R2/R3-verified 64B-row (byte bit5 ^= bit9), 0 conflicts.
// XCD map: each XCD owns a 4MB A-band; all XCDs sweep bn in lockstep (R13:
// FETCH 541->197MB).

using f16x8 = __attribute__((ext_vector_type(8))) _Float16;
using f32x4 = __attribute__((ext_vector_type(4))) float;

#define AS1 __attribute__((address_space(1)))
#define AS3 __attribute__((address_space(3)))

static __device__ __forceinline__ void gload_lds16(const void* g, void* l) {
    __builtin_amdgcn_global_load_lds((const AS1 void*)g, (AS3 void*)l, 16, 0, 0);
}

// ---------------- fused fake-quant: x elementwise + W per-row ----------------
__global__ __launch_bounds__(256) void quant_kernel(
    const float* __restrict__ X,
    const float* __restrict__ las, const float* __restrict__ laq,
    const float* __restrict__ ab,
    const float* __restrict__ W, const float* __restrict__ lws,
    _Float16* __restrict__ Xq, _Float16* __restrict__ Wq) {
    constexpr int K = 2048;
    __shared__ float smn[4], smx[4];
    const int t = threadIdx.x;

    if (blockIdx.x < 8192) {
        // ---- activation fake-quant (elementwise) ----
        const float ls = las[0], lq = laq[0];
        const float s = exp2f(ls);
        const float rs = exp2f(-ls);
        const float q = exp2f(lq);
        const float zp = rintf(ab[0] * rs * 2.0f) * 0.5f * s;  // ACT_GUARD=2
        const float lo = zp;
        const float hi = (zp + q) - s;

        const size_t base = ((size_t)blockIdx.x * 256 + t) * 8;
        float4 v0 = *(const float4*)&X[base];
        float4 v1 = *(const float4*)&X[base + 4];
        float vals[8] = {v0.x, v0.y, v0.z, v0.w, v1.x, v1.y, v1.z, v1.w};

        f16x8 out;
#pragma unroll
        for (int i = 0; i < 8; ++i) {
            float c = fminf(fmaxf(vals[i], lo), hi);
            float qx = rintf((c - zp) * rs);
            out[i] = (_Float16)(qx * s + zp);
        }
        *(f16x8*)&Xq[base] = out;
    } else {
        // ---- weight fake-quant (per-row amin/amax) ----
        const int row = blockIdx.x - 8192;
        const float* w = W + (size_t)row * K;

        float4 v0 = ((const float4*)w)[t * 2];
        float4 v1 = ((const float4*)w)[t * 2 + 1];
        float vals[8] = {v0.x, v0.y, v0.z, v0.w, v1.x, v1.y, v1.z, v1.w};

        float mn = vals[0], mx = vals[0];
#pragma unroll
        for (int i = 1; i < 8; ++i) {
            mn = fminf(mn, vals[i]);
            mx = fmaxf(mx, vals[i]);
        }
#pragma unroll
        for (int off = 32; off >= 1; off >>= 1) {
            mn = fminf(mn, __shfl_xor(mn, off));
            mx = fmaxf(mx, __shfl_xor(mx, off));
        }
        if ((t & 63) == 0) { smn[t >> 6] = mn; smx[t >> 6] = mx; }
        __syncthreads();
        mn = fminf(fminf(smn[0], smn[1]), fminf(smn[2], smn[3]));
        mx = fmaxf(fmaxf(smx[0], smx[1]), fmaxf(smx[2], smx[3]));

        const float l = lws[row];
        const float ws = exp2f(l);     // power of two -> exact
        const float rs = exp2f(-l);    // exact reciprocal
        const float qwmin = rintf(mn * rs * 2.0f) * 0.5f * ws;  // WGT_GUARD=2
        const float qwmax = rintf(mx * rs * 2.0f) * 0.5f * ws;

        f16x8 out;
#pragma unroll
        for (int i = 0; i < 8; ++i) {
            float c = fminf(fmaxf(vals[i], qwmin), qwmax);
            float qw = rintf((c - qwmin) * rs);
            out[i] = (_Float16)(qw * ws + qwmin);
        }
        *(f16x8*)&Wq[(size_t)row * K + (size_t)t * 8] = out;
    }
}

// ---------------- GEMM: C[M][N] = A[M][K] * B[N][K]^T + bias ----------------
// Block tile 256x128, 4 waves (wr=wid>>1 M-half, wc=wid&1 N-half), 128x64/wave.
// LDS 48KB: A [db2][256][32] f16 (2x16KB at 0), B [db2][128][32] (2x8KB at
// +32768). Phase kt (db=kt&1), 64 phases:
//   STAGE(db^1, kt+1): A 4 + B 2 gload_lds per thread
//   12 ds_read_b128 (tile kt from db); lgkm(0); 32 MFMA
//   VMC(0); BAR   (own loads drained BEFORE barrier => after BAR all landed)
// WAR: stage targets db^1 whose readers drained at phase kt-1's lgkm(0),
// one barrier earlier. Last-iter clamp re-stages identical bytes (benign).
__global__ __launch_bounds__(256, 2) void gemm_kernel(
    const _Float16* __restrict__ A, const _Float16* __restrict__ B,
    const float* __restrict__ bias, float* __restrict__ C) {
    constexpr int N = 8192, K = 2048;
    constexpr int KT = K / 32;          // 64 K-steps

    __shared__ char smem[49152];        // A: 0..32K (2 bufs), B: 32K..48K

    // XCD map: xcd = bid&7 owns A-band bm in [4x,4x+4) (4MB -> its L2);
    // j walks bm fastest so all XCDs sweep bn in lockstep (B via L3).
    // Bijective: 8 * 4 * 64 = 2048 = gridDim.
    const int bid = blockIdx.x;
    const int j = bid >> 3;
    const int bm = (bid & 7) * 4 + (j & 3);   // 0..31 (256-row tiles)
    const int bn = j >> 2;                    // 0..63 (128-col tiles)

    const int t = threadIdx.x;
    const int lane = t & 63;
    const int wid = t >> 6;             // 0..3
    const int wr = wid >> 1;            // 0..1 (M half)
    const int wc = wid & 1;             // 0..1 (N half)
    const int l15 = lane & 15;
    const int lq = lane >> 4;

    // staging: rows are 64B (32 k x 2B). Swizzle byte bit5 ^= bit9
    // (bit9 of linear = bit3 of row). Linear dest d = t*16 + i*4096:
    // row_i = (t>>2) + i*64; col (elems) invariant across i.
    const int ra = t >> 2;
    const int ce = (((t & 3) * 16) ^ (((t >> 5) & 1) << 5)) >> 1;
    const _Float16* Agb = A + (size_t)bm * 256 * K;
    const _Float16* Bgb = B + (size_t)bn * 128 * K;

    // read-side swizzled k-col byte offset (bit9 of addr = row bit3 = l15 bit3)
    const int cp = (lq * 16) ^ ((l15 & 8) << 2);

    f32x4 acc[8][4] = {};
    f16x8 fA[8], fB[4];

#define STAGE(DBS, KS) do {                                                    \
        const _Float16* _ga = Agb + (size_t)(KS) * 32 + ce;                    \
        char* _la = smem + (DBS) * 16384 + t * 16;                             \
        gload_lds16(_ga + (size_t)(ra +   0) * K, _la +     0);                \
        gload_lds16(_ga + (size_t)(ra +  64) * K, _la +  4096);                \
        gload_lds16(_ga + (size_t)(ra + 128) * K, _la +  8192);                \
        gload_lds16(_ga + (size_t)(ra + 192) * K, _la + 12288);                \
        const _Float16* _gb = Bgb + (size_t)(KS) * 32 + ce;                    \
        char* _lb = smem + 32768 + (DBS) * 8192 + t * 16;                      \
        gload_lds16(_gb + (size_t)(ra +   0) * K, _lb +     0);                \
        gload_lds16(_gb + (size_t)(ra +  64) * K, _lb +  4096);                \
    } while (0)

#define VMC(NN) asm volatile("s_waitcnt vmcnt(" #NN ")" ::: "memory")
#define BAR()   __builtin_amdgcn_s_barrier()
#define PRIO(P) __builtin_amdgcn_s_setprio(P)

    // ---- prologue: stage tile 0 into db0; drain BEFORE barrier ----
    STAGE(0, 0);
    VMC(0);
    BAR();

    for (int kt = 0; kt < KT; ++kt) {
        const int db = kt & 1;
        const int nx = (kt + 1 < KT) ? kt + 1 : KT - 1;

        STAGE(db ^ 1, nx);               // 6 loads for tile kt+1

        // 12 ds_read_b128: fragments of tile kt
        {
            const char* _a = smem + db * 16384 + (wr * 128 + l15) * 64 + cp;
#pragma unroll
            for (int m = 0; m < 8; ++m)
                fA[m] = *(const f16x8*)(_a + m * 1024);
            const char* _b = smem + 32768 + db * 8192 +
                             (wc * 64 + l15) * 64 + cp;
#pragma unroll
            for (int n = 0; n < 4; ++n)
                fB[n] = *(const f16x8*)(_b + n * 1024);
        }
        asm volatile("s_waitcnt lgkmcnt(0)" ::: "memory");
        __builtin_amdgcn_sched_barrier(0);

        PRIO(1);
#pragma unroll
        for (int m = 0; m < 8; ++m)
#pragma unroll
            for (int n = 0; n < 4; ++n)
                acc[m][n] = __builtin_amdgcn_mfma_f32_16x16x32_f16(
                    fA[m], fB[n], acc[m][n], 0, 0, 0);
        PRIO(0);

        VMC(0);                          // own 6 loads drained (BEFORE BAR)
        BAR();                           // => all waves' loads landed
    }
#undef STAGE
#undef VMC
#undef BAR
#undef PRIO

    // ---- epilogue: C/D mapping col=lane&15, row=(lane>>4)*4+reg ----
#pragma unroll
    for (int m = 0; m < 8; ++m) {
        const int row = bm * 256 + wr * 128 + m * 16 + lq * 4;
#pragma unroll
        for (int n = 0; n < 4; ++n) {
            const int col = bn * 128 + wc * 64 + n * 16 + l15;
            const float bv = bias[col];
#pragma unroll
            for (int r = 0; r < 4; ++r) {
                C[(size_t)(row + r) * N + col] = acc[m][n][r] + bv;
            }
        }
    }
}

extern "C" void kernel_launch(void* const* d_in, const int* in_sizes, int n_in,
                              void* d_out, int out_size, void* d_ws, size_t ws_size,
                              hipStream_t stream) {
    const float* x    = (const float*)d_in[0];   // [4,2048,2048]
    const float* w    = (const float*)d_in[1];   // [8192,2048]
    const float* bias = (const float*)d_in[2];   // [8192]
    const float* las  = (const float*)d_in[3];   // log_act_s [1]
    const float* laq  = (const float*)d_in[4];   // log_act_q [1]
    const float* ab   = (const float*)d_in[5];   // act_b [1]
    const float* lws  = (const float*)d_in[6];   // log_wght_s [8192]
    float* out = (float*)d_out;

    constexpr size_t MK = (size_t)8192 * 2048;
    _Float16* xq = (_Float16*)d_ws;
    _Float16* wq = (_Float16*)((char*)d_ws + MK * sizeof(_Float16));

    quant_kernel<<<16384, 256, 0, stream>>>(x, las, laq, ab, w, lws, xq, wq);
    gemm_kernel<<<2048, 256, 0, stream>>>(xq, wq, bias, out);
}

// Round 15
// 285.815 us; speedup vs baseline: 1.1072x; 1.1072x over previous
//
#include <hip/hip_runtime.h>
#include <hip/hip_bf16.h>

// NoisyActLin: y = fakequant(x) @ fakequant(W).T + bias
// x: [4,2048,2048] f32 -> M=8192, K=2048 ; W: [8192,2048] f32 -> N=8192
// out: [8192, 8192] f32
//
// R15 = R13 (best: 253us GEMM, FETCH 197MB, 0 conflicts) + counted-lgkm
// LADDER: pin ds_read issue order (sched_barrier groups), then start each
// MFMA sub-group as soon as ITS reads retired (DS returns are in-order
// per wave) — the LDS port drains the rest UNDER the MFMAs instead of
// before them (R5..R14 all serialized port+MFMA via flat lgkmcnt(0)).

using f16x8 = __attribute__((ext_vector_type(8))) _Float16;
using f32x4 = __attribute__((ext_vector_type(4))) float;

#define AS1 __attribute__((address_space(1)))
#define AS3 __attribute__((address_space(3)))

static __device__ __forceinline__ void gload_lds16(const void* g, void* l) {
    __builtin_amdgcn_global_load_lds((const AS1 void*)g, (AS3 void*)l, 16, 0, 0);
}

// ---------------- fused fake-quant: x elementwise + W per-row ----------------
__global__ __launch_bounds__(256) void quant_kernel(
    const float* __restrict__ X,
    const float* __restrict__ las, const float* __restrict__ laq,
    const float* __restrict__ ab,
    const float* __restrict__ W, const float* __restrict__ lws,
    _Float16* __restrict__ Xq, _Float16* __restrict__ Wq) {
    constexpr int K = 2048;
    __shared__ float smn[4], smx[4];
    const int t = threadIdx.x;

    if (blockIdx.x < 8192) {
        const float ls = las[0], lq = laq[0];
        const float s = exp2f(ls);
        const float rs = exp2f(-ls);
        const float q = exp2f(lq);
        const float zp = rintf(ab[0] * rs * 2.0f) * 0.5f * s;  // ACT_GUARD=2
        const float lo = zp;
        const float hi = (zp + q) - s;

        const size_t base = ((size_t)blockIdx.x * 256 + t) * 8;
        float4 v0 = *(const float4*)&X[base];
        float4 v1 = *(const float4*)&X[base + 4];
        float vals[8] = {v0.x, v0.y, v0.z, v0.w, v1.x, v1.y, v1.z, v1.w};

        f16x8 out;
#pragma unroll
        for (int i = 0; i < 8; ++i) {
            float c = fminf(fmaxf(vals[i], lo), hi);
            float qx = rintf((c - zp) * rs);
            out[i] = (_Float16)(qx * s + zp);
        }
        *(f16x8*)&Xq[base] = out;
    } else {
        const int row = blockIdx.x - 8192;
        const float* w = W + (size_t)row * K;

        float4 v0 = ((const float4*)w)[t * 2];
        float4 v1 = ((const float4*)w)[t * 2 + 1];
        float vals[8] = {v0.x, v0.y, v0.z, v0.w, v1.x, v1.y, v1.z, v1.w};

        float mn = vals[0], mx = vals[0];
#pragma unroll
        for (int i = 1; i < 8; ++i) {
            mn = fminf(mn, vals[i]);
            mx = fmaxf(mx, vals[i]);
        }
#pragma unroll
        for (int off = 32; off >= 1; off >>= 1) {
            mn = fminf(mn, __shfl_xor(mn, off));
            mx = fmaxf(mx, __shfl_xor(mx, off));
        }
        if ((t & 63) == 0) { smn[t >> 6] = mn; smx[t >> 6] = mx; }
        __syncthreads();
        mn = fminf(fminf(smn[0], smn[1]), fminf(smn[2], smn[3]));
        mx = fmaxf(fmaxf(smx[0], smx[1]), fmaxf(smx[2], smx[3]));

        const float l = lws[row];
        const float ws = exp2f(l);
        const float rs = exp2f(-l);
        const float qwmin = rintf(mn * rs * 2.0f) * 0.5f * ws;  // WGT_GUARD=2
        const float qwmax = rintf(mx * rs * 2.0f) * 0.5f * ws;

        f16x8 out;
#pragma unroll
        for (int i = 0; i < 8; ++i) {
            float c = fminf(fmaxf(vals[i], qwmin), qwmax);
            float qw = rintf((c - qwmin) * rs);
            out[i] = (_Float16)(qw * ws + qwmin);
        }
        *(f16x8*)&Wq[(size_t)row * K + (size_t)t * 8] = out;
    }
}

// ---------------- GEMM: C[M][N] = A[M][K] * B[N][K]^T + bias ----------------
// Structure/ledger == R13 (stage order P1..P8 = b.A0,b.A1,aN.B0,aN.A0 |
// aN.A1,aN.B1,bN.B0,bN.B1; vmcnt(4)@P4/P8; WAR via phase-end barriers).
// NEW: per-phase counted-lgkm ladder (reads in pinned groups; MFMA chunk j
// waits only for its own operands; DS returns in-order per wave).
__global__ __launch_bounds__(512, 2) void gemm_kernel(
    const _Float16* __restrict__ A, const _Float16* __restrict__ B,
    const float* __restrict__ bias, float* __restrict__ C) {
    constexpr int N = 8192, K = 2048;
    constexpr int KT = K / 64;          // 32 K-tiles, 16 iterations

    __shared__ char smem[131072];       // A: 0..64K, B: 64K..128K

    // L2/L3-aware mapping (R13): XCD x owns A-band [4x,4x+4); bm fastest.
    const int bid = blockIdx.x;
    const int j = bid >> 3;
    const int bm = (bid & 7) * 4 + (j & 3);
    const int bn = j >> 2;

    const int t = threadIdx.x;
    const int lane = t & 63;
    const int wid = t >> 6;
    const int wr = wid >> 2;            // 0..1 (M half)
    const int wc = wid & 3;             // 0..3 (N quarter)
    const int l15 = lane & 15;
    const int lq = lane >> 4;

    // staging: half-tile [128][64] f16 = 16KB, linear dest, pre-swizzled
    // source. T2 swizzle: byte ^= (row&7)<<4 (verified 0 conflicts).
    const int d0 = t * 16, d1 = d0 + 8192;
    const int r0 = d0 >> 7, c0 = (((d0 & 127) ^ (((d0 >> 7) & 7) << 4)) >> 1);
    const int r1 = d1 >> 7, c1 = (((d1 & 127) ^ (((d1 >> 7) & 7) << 4)) >> 1);
    const _Float16* Agb = A + (size_t)bm * 256 * K;
    const _Float16* Bgb = B + (size_t)bn * 256 * K;

    const int cp0 = (lq * 16) ^ ((l15 & 7) << 4);
    const int cp1 = cp0 ^ 64;

    f32x4 acc[8][4] = {};
    f16x8 fA0[4][2], fA1[4][2], fB0[2][2], fB1[2][2];

#define STAGE(GB, RO, DBS, H, KS) do {                                         \
        const _Float16* _g = (GB) + (size_t)((H) * 128) * K + (size_t)(KS) * 64;\
        char* _l = smem + (RO) + ((DBS) * 2 + (H)) * 16384;                    \
        gload_lds16(_g + (size_t)r0 * K + c0, _l + d0);                        \
        gload_lds16(_g + (size_t)r1 * K + c1, _l + d1);                        \
    } while (0)

// single fragment reads (pinned-order building blocks)
#define RA(dst, MI, KI, DBv, MB)                                               \
    dst[MI][KI] = *(const f16x8*)(smem + ((DBv) * 2 + wr) * 16384 +            \
        l15 * 128 + ((MB) + (MI)) * 2048 + ((KI) ? cp1 : cp0))
#define RB(dst, NI, KI, DBv, NB)                                               \
    dst[NI][KI] = *(const f16x8*)(smem + 65536 + ((DBv) * 2 + (wc >> 1)) *     \
        16384 + (wc & 1) * 8192 + l15 * 128 + ((NB) + (NI)) * 2048 +           \
        ((KI) ? cp1 : cp0))

#define MM(AM, AN, AFm, BFn) do {                                              \
        f32x4 _c = acc[AM][AN];                                                \
        _c = __builtin_amdgcn_mfma_f32_16x16x32_f16((AFm)[0], (BFn)[0], _c,    \
                                                    0, 0, 0);                  \
        _c = __builtin_amdgcn_mfma_f32_16x16x32_f16((AFm)[1], (BFn)[1], _c,    \
                                                    0, 0, 0);                  \
        acc[AM][AN] = _c;                                                      \
    } while (0)

#define SB()    __builtin_amdgcn_sched_barrier(0)
#define LG(NN) do {                                                            \
        asm volatile("s_waitcnt lgkmcnt(" #NN ")" ::: "memory");               \
        __builtin_amdgcn_sched_barrier(0);                                     \
    } while (0)
#define VMC(NN) asm volatile("s_waitcnt vmcnt(" #NN ")" ::: "memory")
#define BAR()   __builtin_amdgcn_s_barrier()
#define PRIO(P) __builtin_amdgcn_s_setprio(P)

// one K-tile = 4 phases, ladder inside each.
#define HALFITER(DBv, S1, S2, S3, S4, VMW) do {                                \
        /* ---- P1: 12 reads (pinned), ladder over (m0..3 x n0,n1) ---- */     \
        RA(fA0,0,0,DBv,0); RA(fA0,0,1,DBv,0);                                  \
        RB(fB0,0,0,DBv,0); RB(fB0,0,1,DBv,0); SB();                            \
        RB(fB0,1,0,DBv,0); RB(fB0,1,1,DBv,0); SB();                            \
        RA(fA0,1,0,DBv,0); RA(fA0,1,1,DBv,0); SB();                            \
        RA(fA0,2,0,DBv,0); RA(fA0,2,1,DBv,0); SB();                            \
        RA(fA0,3,0,DBv,0); RA(fA0,3,1,DBv,0); SB();                            \
        S1;                                                                    \
        BAR();                                                                 \
        PRIO(1);                                                               \
        LG(8);  MM(0,0,fA0[0],fB0[0]);                                         \
        LG(6);  MM(0,1,fA0[0],fB0[1]);                                         \
        LG(4);  MM(1,0,fA0[1],fB0[0]); MM(1,1,fA0[1],fB0[1]);                  \
        LG(2);  MM(2,0,fA0[2],fB0[0]); MM(2,1,fA0[2],fB0[1]);                  \
        LG(0);  MM(3,0,fA0[3],fB0[0]); MM(3,1,fA0[3],fB0[1]);                  \
        PRIO(0);                                                               \
        BAR();                                                                 \
        /* ---- P2: 4 reads, ladder over n2,n3 columns ---- */                 \
        RB(fB1,0,0,DBv,2); RB(fB1,0,1,DBv,2); SB();                            \
        RB(fB1,1,0,DBv,2); RB(fB1,1,1,DBv,2); SB();                            \
        S2;                                                                    \
        BAR();                                                                 \
        PRIO(1);                                                               \
        LG(2);  MM(0,2,fA0[0],fB1[0]); MM(1,2,fA0[1],fB1[0]);                  \
                MM(2,2,fA0[2],fB1[0]); MM(3,2,fA0[3],fB1[0]);                  \
        LG(0);  MM(0,3,fA0[0],fB1[1]); MM(1,3,fA0[1],fB1[1]);                  \
                MM(2,3,fA0[2],fB1[1]); MM(3,3,fA0[3],fB1[1]);                  \
        PRIO(0);                                                               \
        BAR();                                                                 \
        /* ---- P3: 8 reads, ladder over m4..7 ---- */                         \
        RA(fA1,0,0,DBv,4); RA(fA1,0,1,DBv,4); SB();                            \
        RA(fA1,1,0,DBv,4); RA(fA1,1,1,DBv,4); SB();                            \
        RA(fA1,2,0,DBv,4); RA(fA1,2,1,DBv,4); SB();                            \
        RA(fA1,3,0,DBv,4); RA(fA1,3,1,DBv,4); SB();                            \
        S3;                                                                    \
        BAR();                                                                 \
        PRIO(1);                                                               \
        LG(6);  MM(4,2,fA1[0],fB1[0]); MM(4,3,fA1[0],fB1[1]);                  \
        LG(4);  MM(5,2,fA1[1],fB1[0]); MM(5,3,fA1[1],fB1[1]);                  \
        LG(2);  MM(6,2,fA1[2],fB1[0]); MM(6,3,fA1[2],fB1[1]);                  \
        LG(0);  MM(7,2,fA1[3],fB1[0]); MM(7,3,fA1[3],fB1[1]);                  \
        PRIO(0);                                                               \
        BAR();                                                                 \
        /* ---- P4: 0 reads ---- */                                            \
        S4;                                                                    \
        BAR();                                                                 \
        PRIO(1);                                                               \
        MM(4,0,fA1[0],fB0[0]); MM(4,1,fA1[0],fB0[1]);                          \
        MM(5,0,fA1[1],fB0[0]); MM(5,1,fA1[1],fB0[1]);                          \
        MM(6,0,fA1[2],fB0[0]); MM(6,1,fA1[2],fB0[1]);                          \
        MM(7,0,fA1[3],fB0[0]); MM(7,1,fA1[3],fB0[1]);                          \
        PRIO(0);                                                               \
        VMC(VMW);                                                              \
        BAR();                                                                 \
    } while (0)

    // ---- prologue: stage t0 all + t1.B0/B1; wait t0 landed ----
    STAGE(Bgb, 65536, 0, 0, 0);   // t0.B0
    STAGE(Agb, 0,     0, 0, 0);   // t0.A0
    STAGE(Agb, 0,     0, 1, 0);   // t0.A1
    STAGE(Bgb, 65536, 0, 1, 0);   // t0.B1
    STAGE(Bgb, 65536, 1, 0, 1);   // t1.B0
    STAGE(Bgb, 65536, 1, 1, 1);   // t1.B1
    VMC(4);
    BAR();

    for (int it = 0; it < KT / 2; ++it) {
        const int b  = 2 * it + 1;
        const int aN = (2 * it + 2 < KT) ? 2 * it + 2 : KT - 2;
        const int bN = (2 * it + 3 < KT) ? 2 * it + 3 : KT - 1;

        // tile a (db0): stages P1..P4 = b.A0, b.A1, aN.B0, aN.A0
        HALFITER(0,
                 STAGE(Agb, 0,     1, 0, b),
                 STAGE(Agb, 0,     1, 1, b),
                 STAGE(Bgb, 65536, 0, 0, aN),
                 STAGE(Agb, 0,     0, 0, aN), 4);
        // tile b (db1): stages P5..P8 = aN.A1, aN.B1, bN.B0, bN.B1
        HALFITER(1,
                 STAGE(Agb, 0,     0, 1, aN),
                 STAGE(Bgb, 65536, 0, 1, aN),
                 STAGE(Bgb, 65536, 1, 0, bN),
                 STAGE(Bgb, 65536, 1, 1, bN), 4);
    }
#undef HALFITER
#undef MM
#undef RA
#undef RB
#undef LG
#undef SB
#undef VMC
#undef BAR
#undef PRIO
#undef STAGE

    // ---- epilogue: C/D mapping col=lane&15, row=(lane>>4)*4+reg ----
#pragma unroll
    for (int m = 0; m < 8; ++m) {
        const int row = bm * 256 + wr * 128 + m * 16 + lq * 4;
#pragma unroll
        for (int n = 0; n < 4; ++n) {
            const int col = bn * 256 + wc * 64 + n * 16 + l15;
            const float bv = bias[col];
#pragma unroll
            for (int r = 0; r < 4; ++r) {
                C[(size_t)(row + r) * N + col] = acc[m][n][r] + bv;
            }
        }
    }
}

extern "C" void kernel_launch(void* const* d_in, const int* in_sizes, int n_in,
                              void* d_out, int out_size, void* d_ws, size_t ws_size,
                              hipStream_t stream) {
    const float* x    = (const float*)d_in[0];   // [4,2048,2048]
    const float* w    = (const float*)d_in[1];   // [8192,2048]
    const float* bias = (const float*)d_in[2];   // [8192]
    const float* las  = (const float*)d_in[3];   // log_act_s [1]
    const float* laq  = (const float*)d_in[4];   // log_act_q [1]
    const float* ab   = (const float*)d_in[5];   // act_b [1]
    const float* lws  = (const float*)d_in[6];   // log_wght_s [8192]
    float* out = (float*)d_out;

    constexpr size_t MK = (size_t)8192 * 2048;
    _Float16* xq = (_Float16*)d_ws;
    _Float16* wq = (_Float16*)((char*)d_ws + MK * sizeof(_Float16));

    quant_kernel<<<16384, 256, 0, stream>>>(x, las, laq, ab, w, lws, xq, wq);
    gemm_kernel<<<1024, 512, 0, stream>>>(xq, wq, bias, out);
}

// Round 16
// 278.932 us; speedup vs baseline: 1.1345x; 1.0247x over previous
//
#include <hip/hip_runtime.h>
#include <hip/hip_bf16.h>

// NoisyActLin: y = fakequant(x) @ fakequant(W).T + bias
// x: [4,2048,2048] f32 -> M=8192, K=2048 ; W: [8192,2048] f32 -> N=8192
// out: [8192, 8192] f32
//
// R16 = R13 (best: 253us GEMM) minus the "memory" clobbers on intra-phase
// lgkm waits. Diagnosis: clobbered asm pinned every ds_read between fences
// -> [reads][drain][MFMA] serialized (4784 cyc/K-tile, measured 4743-4970
// across R5..R15). m201's template uses PLAIN volatile asm: the compiler may
// float compiler-visible ds_reads across raw s_barrier (no mem semantics)
// and software-pipeline them into MFMA clusters with its own counted lgkm
// (m97). Ideal-overlap bound 3160 cyc/K-tile == m201's measured 2981-3296.
// vmcnt KEEPS "memory": pins stage order (WAR) and bounds read-hoisting at
// exactly the landing-guarantee point (P4/P8).

using f16x8 = __attribute__((ext_vector_type(8))) _Float16;
using f32x4 = __attribute__((ext_vector_type(4))) float;

#define AS1 __attribute__((address_space(1)))
#define AS3 __attribute__((address_space(3)))

static __device__ __forceinline__ void gload_lds16(const void* g, void* l) {
    __builtin_amdgcn_global_load_lds((const AS1 void*)g, (AS3 void*)l, 16, 0, 0);
}

// ---------------- fused fake-quant: x elementwise + W per-row ----------------
__global__ __launch_bounds__(256) void quant_kernel(
    const float* __restrict__ X,
    const float* __restrict__ las, const float* __restrict__ laq,
    const float* __restrict__ ab,
    const float* __restrict__ W, const float* __restrict__ lws,
    _Float16* __restrict__ Xq, _Float16* __restrict__ Wq) {
    constexpr int K = 2048;
    __shared__ float smn[4], smx[4];
    const int t = threadIdx.x;

    if (blockIdx.x < 8192) {
        const float ls = las[0], lq = laq[0];
        const float s = exp2f(ls);
        const float rs = exp2f(-ls);
        const float q = exp2f(lq);
        const float zp = rintf(ab[0] * rs * 2.0f) * 0.5f * s;  // ACT_GUARD=2
        const float lo = zp;
        const float hi = (zp + q) - s;

        const size_t base = ((size_t)blockIdx.x * 256 + t) * 8;
        float4 v0 = *(const float4*)&X[base];
        float4 v1 = *(const float4*)&X[base + 4];
        float vals[8] = {v0.x, v0.y, v0.z, v0.w, v1.x, v1.y, v1.z, v1.w};

        f16x8 out;
#pragma unroll
        for (int i = 0; i < 8; ++i) {
            float c = fminf(fmaxf(vals[i], lo), hi);
            float qx = rintf((c - zp) * rs);
            out[i] = (_Float16)(qx * s + zp);
        }
        *(f16x8*)&Xq[base] = out;
    } else {
        const int row = blockIdx.x - 8192;
        const float* w = W + (size_t)row * K;

        float4 v0 = ((const float4*)w)[t * 2];
        float4 v1 = ((const float4*)w)[t * 2 + 1];
        float vals[8] = {v0.x, v0.y, v0.z, v0.w, v1.x, v1.y, v1.z, v1.w};

        float mn = vals[0], mx = vals[0];
#pragma unroll
        for (int i = 1; i < 8; ++i) {
            mn = fminf(mn, vals[i]);
            mx = fmaxf(mx, vals[i]);
        }
#pragma unroll
        for (int off = 32; off >= 1; off >>= 1) {
            mn = fminf(mn, __shfl_xor(mn, off));
            mx = fmaxf(mx, __shfl_xor(mx, off));
        }
        if ((t & 63) == 0) { smn[t >> 6] = mn; smx[t >> 6] = mx; }
        __syncthreads();
        mn = fminf(fminf(smn[0], smn[1]), fminf(smn[2], smn[3]));
        mx = fmaxf(fmaxf(smx[0], smx[1]), fmaxf(smx[2], smx[3]));

        const float l = lws[row];
        const float ws = exp2f(l);
        const float rs = exp2f(-l);
        const float qwmin = rintf(mn * rs * 2.0f) * 0.5f * ws;  // WGT_GUARD=2
        const float qwmax = rintf(mx * rs * 2.0f) * 0.5f * ws;

        f16x8 out;
#pragma unroll
        for (int i = 0; i < 8; ++i) {
            float c = fminf(fmaxf(vals[i], qwmin), qwmax);
            float qw = rintf((c - qwmin) * rs);
            out[i] = (_Float16)(qw * ws + qwmin);
        }
        *(f16x8*)&Wq[(size_t)row * K + (size_t)t * 8] = out;
    }
}

// ---------------- GEMM: C[M][N] = A[M][K] * B[N][K]^T + bias ----------------
// Structure/ledger == R13 (stage order P1..P8 = b.A0,b.A1,aN.B0,aN.A0 |
// aN.A1,aN.B1,bN.B0,bN.B1; vmcnt(4)@P4/P8 WITH "memory"; WAR via barriers +
// compiler LDS alias analysis). Intra-phase lgkm waits are PLAIN volatile
// asm (no clobber) so the compiler may pipeline reads into MFMA clusters.
__global__ __launch_bounds__(512, 2) void gemm_kernel(
    const _Float16* __restrict__ A, const _Float16* __restrict__ B,
    const float* __restrict__ bias, float* __restrict__ C) {
    constexpr int N = 8192, K = 2048;
    constexpr int KT = K / 64;          // 32 K-tiles, 16 iterations

    __shared__ char smem[131072];       // A: 0..64K, B: 64K..128K

    // L2/L3-aware mapping (R13): XCD x owns A-band [4x,4x+4); bm fastest.
    const int bid = blockIdx.x;
    const int j = bid >> 3;
    const int bm = (bid & 7) * 4 + (j & 3);
    const int bn = j >> 2;

    const int t = threadIdx.x;
    const int lane = t & 63;
    const int wid = t >> 6;
    const int wr = wid >> 2;            // 0..1 (M half)
    const int wc = wid & 3;             // 0..3 (N quarter)
    const int l15 = lane & 15;
    const int lq = lane >> 4;

    // staging: half-tile [128][64] f16 = 16KB, linear dest, pre-swizzled
    // source. T2 swizzle: byte ^= (row&7)<<4 (verified 0 conflicts).
    const int d0 = t * 16, d1 = d0 + 8192;
    const int r0 = d0 >> 7, c0 = (((d0 & 127) ^ (((d0 >> 7) & 7) << 4)) >> 1);
    const int r1 = d1 >> 7, c1 = (((d1 & 127) ^ (((d1 >> 7) & 7) << 4)) >> 1);
    const _Float16* Agb = A + (size_t)bm * 256 * K;
    const _Float16* Bgb = B + (size_t)bn * 256 * K;

    const int cp0 = (lq * 16) ^ ((l15 & 7) << 4);
    const int cp1 = cp0 ^ 64;

    f32x4 acc[8][4] = {};
    f16x8 fA0[4][2], fA1[4][2], fB0[2][2], fB1[2][2];

#define STAGE(GB, RO, DBS, H, KS) do {                                         \
        const _Float16* _g = (GB) + (size_t)((H) * 128) * K + (size_t)(KS) * 64;\
        char* _l = smem + (RO) + ((DBS) * 2 + (H)) * 16384;                    \
        gload_lds16(_g + (size_t)r0 * K + c0, _l + d0);                        \
        gload_lds16(_g + (size_t)r1 * K + c1, _l + d1);                        \
    } while (0)

#define LDAF(dst, DBv, MLO) do {                                               \
        const char* _s = smem + ((DBv) * 2 + wr) * 16384 + l15 * 128;          \
        _Pragma("unroll")                                                      \
        for (int _m = 0; _m < 4; ++_m) {                                       \
            dst[_m][0] = *(const f16x8*)(_s + ((MLO) + _m) * 2048 + cp0);      \
            dst[_m][1] = *(const f16x8*)(_s + ((MLO) + _m) * 2048 + cp1);      \
        }                                                                      \
    } while (0)

#define LDBF(dst, DBv, NLO) do {                                               \
        const char* _s = smem + 65536 + ((DBv) * 2 + (wc >> 1)) * 16384 +      \
                         (wc & 1) * 8192 + l15 * 128;                          \
        _Pragma("unroll")                                                      \
        for (int _n = 0; _n < 2; ++_n) {                                       \
            dst[_n][0] = *(const f16x8*)(_s + ((NLO) + _n) * 2048 + cp0);      \
            dst[_n][1] = *(const f16x8*)(_s + ((NLO) + _n) * 2048 + cp1);      \
        }                                                                      \
    } while (0)

#define QMFMA(MLO, NLO, AF, BF) do {                                           \
        _Pragma("unroll")                                                      \
        for (int _m = 0; _m < 4; ++_m)                                         \
            _Pragma("unroll")                                                  \
            for (int _n = 0; _n < 2; ++_n) {                                   \
                f32x4 _c = acc[(MLO) + _m][(NLO) + _n];                        \
                _c = __builtin_amdgcn_mfma_f32_16x16x32_f16(                   \
                    AF[_m][0], BF[_n][0], _c, 0, 0, 0);                        \
                _c = __builtin_amdgcn_mfma_f32_16x16x32_f16(                   \
                    AF[_m][1], BF[_n][1], _c, 0, 0, 0);                        \
                acc[(MLO) + _m][(NLO) + _n] = _c;                              \
            }                                                                  \
    } while (0)

// one K-tile = 4 phases. PLAIN lgkm waits (no memory clobber) — the single
// change vs R13. vmcnt keeps "memory" (stage-order + hoist bound).
#define HALFITER(DBv, S1, S2, S3, S4, VMW) do {                                \
        /* P1: 12 ds_reads */                                                  \
        LDAF(fA0, DBv, 0); LDBF(fB0, DBv, 0);                                  \
        S1;                                                                    \
        asm volatile("s_waitcnt lgkmcnt(8)");                                  \
        __builtin_amdgcn_s_barrier();                                          \
        asm volatile("s_waitcnt lgkmcnt(0)");                                  \
        __builtin_amdgcn_s_setprio(1);                                         \
        QMFMA(0, 0, fA0, fB0);                                                 \
        __builtin_amdgcn_s_setprio(0);                                         \
        __builtin_amdgcn_s_barrier();                                          \
        /* P2: 4 ds_reads */                                                   \
        LDBF(fB1, DBv, 2);                                                     \
        S2;                                                                    \
        __builtin_amdgcn_s_barrier();                                          \
        asm volatile("s_waitcnt lgkmcnt(0)");                                  \
        __builtin_amdgcn_s_setprio(1);                                         \
        QMFMA(0, 2, fA0, fB1);                                                 \
        __builtin_amdgcn_s_setprio(0);                                         \
        __builtin_amdgcn_s_barrier();                                          \
        /* P3: 8 ds_reads */                                                   \
        LDAF(fA1, DBv, 4);                                                     \
        S3;                                                                    \
        __builtin_amdgcn_s_barrier();                                          \
        asm volatile("s_waitcnt lgkmcnt(0)");                                  \
        __builtin_amdgcn_s_setprio(1);                                         \
        QMFMA(4, 2, fA1, fB1);                                                 \
        __builtin_amdgcn_s_setprio(0);                                         \
        __builtin_amdgcn_s_barrier();                                          \
        /* P4: 0 ds_reads */                                                   \
        S4;                                                                    \
        __builtin_amdgcn_s_barrier();                                          \
        __builtin_amdgcn_s_setprio(1);                                         \
        QMFMA(4, 0, fA1, fB0);                                                 \
        __builtin_amdgcn_s_setprio(0);                                         \
        asm volatile("s_waitcnt vmcnt(" #VMW ")" ::: "memory");                \
        __builtin_amdgcn_s_barrier();                                          \
    } while (0)

    // ---- prologue: stage t0 all + t1.B0/B1; wait t0 landed ----
    STAGE(Bgb, 65536, 0, 0, 0);   // t0.B0
    STAGE(Agb, 0,     0, 0, 0);   // t0.A0
    STAGE(Agb, 0,     0, 1, 0);   // t0.A1
    STAGE(Bgb, 65536, 0, 1, 0);   // t0.B1
    STAGE(Bgb, 65536, 1, 0, 1);   // t1.B0
    STAGE(Bgb, 65536, 1, 1, 1);   // t1.B1
    asm volatile("s_waitcnt vmcnt(4)" ::: "memory");
    __builtin_amdgcn_s_barrier();

    for (int it = 0; it < KT / 2; ++it) {
        const int b  = 2 * it + 1;
        const int aN = (2 * it + 2 < KT) ? 2 * it + 2 : KT - 2;
        const int bN = (2 * it + 3 < KT) ? 2 * it + 3 : KT - 1;

        // tile a (db0): stages P1..P4 = b.A0, b.A1, aN.B0, aN.A0
        HALFITER(0,
                 STAGE(Agb, 0,     1, 0, b),
                 STAGE(Agb, 0,     1, 1, b),
                 STAGE(Bgb, 65536, 0, 0, aN),
                 STAGE(Agb, 0,     0, 0, aN), 4);
        // tile b (db1): stages P5..P8 = aN.A1, aN.B1, bN.B0, bN.B1
        HALFITER(1,
                 STAGE(Agb, 0,     0, 1, aN),
                 STAGE(Bgb, 65536, 0, 1, aN),
                 STAGE(Bgb, 65536, 1, 0, bN),
                 STAGE(Bgb, 65536, 1, 1, bN), 4);
    }
#undef HALFITER
#undef QMFMA
#undef LDBF
#undef LDAF
#undef STAGE

    // ---- epilogue: C/D mapping col=lane&15, row=(lane>>4)*4+reg ----
#pragma unroll
    for (int m = 0; m < 8; ++m) {
        const int row = bm * 256 + wr * 128 + m * 16 + lq * 4;
#pragma unroll
        for (int n = 0; n < 4; ++n) {
            const int col = bn * 256 + wc * 64 + n * 16 + l15;
            const float bv = bias[col];
#pragma unroll
            for (int r = 0; r < 4; ++r) {
                C[(size_t)(row + r) * N + col] = acc[m][n][r] + bv;
            }
        }
    }
}

extern "C" void kernel_launch(void* const* d_in, const int* in_sizes, int n_in,
                              void* d_out, int out_size, void* d_ws, size_t ws_size,
                              hipStream_t stream) {
    const float* x    = (const float*)d_in[0];   // [4,2048,2048]
    const float* w    = (const float*)d_in[1];   // [8192,2048]
    const float* bias = (const float*)d_in[2];   // [8192]
    const float* las  = (const float*)d_in[3];   // log_act_s [1]
    const float* laq  = (const float*)d_in[4];   // log_act_q [1]
    const float* ab   = (const float*)d_in[5];   // act_b [1]
    const float* lws  = (const float*)d_in[6];   // log_wght_s [8192]
    float* out = (float*)d_out;

    constexpr size_t MK = (size_t)8192 * 2048;
    _Float16* xq = (_Float16*)d_ws;
    _Float16* wq = (_Float16*)((char*)d_ws + MK * sizeof(_Float16));

    quant_kernel<<<16384, 256, 0, stream>>>(x, las, laq, ab, w, lws, xq, wq);
    gemm_kernel<<<1024, 512, 0, stream>>>(xq, wq, bias, out);
}